// Round 7
// baseline (1211.340 us; speedup 1.0000x reference)
//
// Round 7: n-fastest XCD ordering (A-tile L2-resident, q L3-resident) + LDP=64 with
// 16B-block XOR swizzle (conflict-free writes/reads) + coalesced A staging + occupancy 4.
// Two-pass: (1) pack q->4bit, x->fp16 in d_ws; (2) fused-dequant fp16 MFMA GEMM 128x128x64.
#include <hip/hip_runtime.h>
#include <stdint.h>

#define TOKENS 8192
#define KDIM   4096
#define NDIM   11008
#define BM 128
#define BN 128
#define BK 64
#define QWPR 512                    // packed dwords per q row (4096/8)
#define PQ_BYTES (45088768u/8u*4u)  // 22544384
#define XH_BYTES (33554432ull*2ull) // 67108864
#define WS_NEED  (PQ_BYTES + XH_BYTES)

typedef _Float16 f16x8 __attribute__((ext_vector_type(8)));
typedef float    f32x4 __attribute__((ext_vector_type(4)));

// ---------------- pass 1a: pack 8 int32 (4-bit values) -> 1 dword ----------------
__global__ __launch_bounds__(256) void pack_q(const int* __restrict__ q,
                                              unsigned int* __restrict__ pq) {
    const unsigned int idx = blockIdx.x * 256 + threadIdx.x;
    const int4* p = (const int4*)(q + (size_t)idx * 8);
    const int4 a = p[0], b = p[1];
    unsigned int w = (unsigned int)(a.x & 15)
                   | ((unsigned int)(a.y & 15) << 4)
                   | ((unsigned int)(a.z & 15) << 8)
                   | ((unsigned int)(a.w & 15) << 12)
                   | ((unsigned int)(b.x & 15) << 16)
                   | ((unsigned int)(b.y & 15) << 20)
                   | ((unsigned int)(b.z & 15) << 24)
                   | ((unsigned int)(b.w & 15) << 28);
    pq[idx] = w;
}

// ---------------- pass 1b: x fp32 -> fp16 (exact: data is fp16-valued) ----------------
__global__ __launch_bounds__(256) void cvt_x(const float* __restrict__ x,
                                             _Float16* __restrict__ xh) {
    const size_t idx = (size_t)(blockIdx.x * 256 + threadIdx.x) * 8;
    const float4* p = (const float4*)(x + idx);
    const float4 a = p[0], b = p[1];
    f16x8 o;
    o[0] = (_Float16)a.x; o[1] = (_Float16)a.y; o[2] = (_Float16)a.z; o[3] = (_Float16)a.w;
    o[4] = (_Float16)b.x; o[5] = (_Float16)b.y; o[6] = (_Float16)b.z; o[7] = (_Float16)b.w;
    *(f16x8*)(xh + idx) = o;
}

// ---------------- pass 2: fused-dequant GEMM ----------------
// LDS: [row][8 blocks of 16B]; physical block = logical ^ (row & 7)  (T2-style swizzle)
__global__ __launch_bounds__(256, 4)
void wq_gemm_p(const _Float16* __restrict__ Xh, const unsigned int* __restrict__ Pq,
               const float* __restrict__ Sc, const float* __restrict__ Zp,
               const float* __restrict__ Bi, float* __restrict__ Out)
{
    __shared__ __align__(16) _Float16 As[BM * BK];   // 16 KB
    __shared__ __align__(16) _Float16 Bs[BN * BK];   // 16 KB

    const int t    = threadIdx.x;
    const int lane = t & 63;
    const int wid  = t >> 6;
    const int wr   = wid >> 1;                  // 2x2 waves; 64x64 out each
    const int wc   = wid & 1;

    // XCD-bijective swizzle (5504 = 8*688), n FASTEST within a chunk:
    // consecutive wgs share m0 -> A-tile (1 MiB) L2-resident; q panels stream from L3.
    const unsigned int bid = blockIdx.x;
    const unsigned int wg  = (bid & 7u) * 688u + (bid >> 3);
    const int m0 = (int)(wg / 86u) * BM;
    const int n0 = (int)(wg % 86u) * BN;

    // ---- A staging: 8 lanes cover one row's 128 B (coalesced); 4 rows per thread ----
    const int arow = t >> 3;                    // 0..31 (+rr*32)
    const int ablk = t & 7;                     // 16B block within row
    const _Float16* asrc = Xh + (size_t)(m0 + arow) * KDIM + ablk * 8;
    const int apos = ((ablk ^ (arow & 7)) << 3);           // swizzled elem offset in row
    _Float16* adst0 = As + arow * BK + apos;               // +rr*32*BK per rr

    // ---- B staging: 2 threads per row, 16B packed q each -> 64B fp16 out ----
    const int brow  = t >> 1;
    const int bhalf = t & 1;
    const unsigned int* qsrc = Pq + (size_t)(n0 + brow) * QWPR + bhalf * 4;
    const float* scp = Sc + n0 + brow;
    const float* zpp = Zp + n0 + brow;
    const int bxor = brow & 7;
    _Float16* bdst[4];
#pragma unroll
    for (int d = 0; d < 4; ++d)
        bdst[d] = Bs + brow * BK + (((bhalf * 4 + d) ^ bxor) << 3);

    // ---- fragment read map (16x16x32 f16: lane -> row lane&15, k=(lane>>4)*8..+7) ----
    const int fr = lane & 15;
    const int fq = lane >> 4;
    const int fxor = fr & 7;
    // k-block for kk half: kk*4 + fq, physical = ^fxor
    const int offk0 = ((0 * 4 + fq) ^ fxor) << 3;
    const int offk1 = ((1 * 4 + fq) ^ fxor) << 3;

    f32x4 acc[4][4];
#pragma unroll
    for (int i = 0; i < 4; ++i)
#pragma unroll
        for (int j = 0; j < 4; ++j)
            acc[i][j] = f32x4{0.f, 0.f, 0.f, 0.f};

    for (int kt = 0; kt < KDIM / BK; ++kt) {
        // A: 4 coalesced b128 loads (per instr: wave reads 8 rows x 128B contiguous)
        f16x8 av[4];
#pragma unroll
        for (int rr = 0; rr < 4; ++rr)
            av[rr] = *(const f16x8*)(asrc + (size_t)rr * 32 * KDIM + kt * BK);

        // B: 4 packed dwords = 32 nibbles; dequant f32 -> fp16 (single rounding).
        const int g = kt >> 1;
        const float sf = scp[(size_t)g * NDIM];
        const float zf = zpp[(size_t)g * NDIM];
        const uint4 pw = *(const uint4*)(qsrc + kt * 8);
        const unsigned int pv[4] = {pw.x, pw.y, pw.z, pw.w};
        f16x8 w[4];
#pragma unroll
        for (int d = 0; d < 4; ++d)
#pragma unroll
            for (int j = 0; j < 8; ++j)
                w[d][j] = (_Float16)((float)((pv[d] >> (4 * j)) & 15u) * sf + zf);

        // stage (swizzled, conflict-free: every 16-lane beat covers all 8 bank-quads <=2-way)
#pragma unroll
        for (int rr = 0; rr < 4; ++rr)
            *(f16x8*)(adst0 + rr * 32 * BK) = av[rr];
#pragma unroll
        for (int d = 0; d < 4; ++d)
            *(f16x8*)bdst[d] = w[d];

        __syncthreads();

#pragma unroll
        for (int kk = 0; kk < 2; ++kk) {
            const int offk = kk ? offk1 : offk0;
            f16x8 a[4], b[4];
#pragma unroll
            for (int i = 0; i < 4; ++i)
                a[i] = *(const f16x8*)(As + (wr * 64 + i * 16 + fr) * BK + offk);
#pragma unroll
            for (int j = 0; j < 4; ++j)
                b[j] = *(const f16x8*)(Bs + (wc * 64 + j * 16 + fr) * BK + offk);
#pragma unroll
            for (int i = 0; i < 4; ++i)
#pragma unroll
                for (int j = 0; j < 4; ++j)
                    acc[i][j] = __builtin_amdgcn_mfma_f32_16x16x32_f16(a[i], b[j], acc[i][j], 0, 0, 0);
        }

        __syncthreads();
    }

    // ---- epilogue: C/D map col=lane&15, row=(lane>>4)*4+reg; out = f32(f16(acc)+f16(bias))
#pragma unroll
    for (int j = 0; j < 4; ++j) {
        const int n = n0 + wc * 64 + j * 16 + fr;
        const _Float16 bv = (_Float16)Bi[n];
#pragma unroll
        for (int i = 0; i < 4; ++i) {
            const int mbase = m0 + wr * 64 + i * 16 + fq * 4;
#pragma unroll
            for (int r = 0; r < 4; ++r) {
                const _Float16 h = (_Float16)acc[i][j][r] + bv;
                Out[(size_t)(mbase + r) * NDIM + n] = (float)h;
            }
        }
    }
}

// ---------------- fallback: round-5 direct kernel (no workspace) ----------------
__global__ __launch_bounds__(256, 2)
void wq_gemm_direct(const float* __restrict__ X,  const int* __restrict__ Qw,
                    const float* __restrict__ Sc, const float* __restrict__ Zp,
                    const float* __restrict__ Bi, float* __restrict__ Out)
{
    __shared__ __align__(16) _Float16 As[BM * 32];
    __shared__ __align__(16) _Float16 Bs[BN * 32];
    const int t = threadIdx.x, lane = t & 63, wid = t >> 6;
    const int wr = wid >> 1, wc = wid & 1;
    const int n0 = blockIdx.x * BN, m0 = blockIdx.y * BM;
    const int srow = t >> 1, shalf = (t & 1) << 4;
    const float* xsrc = X + (size_t)(m0 + srow) * KDIM + shalf;
    const int*   qsrc = Qw + (size_t)(n0 + srow) * KDIM + shalf;
    const float* scp = Sc + n0 + srow;
    const float* zpp = Zp + n0 + srow;
    _Float16* adst = As + srow * 32 + shalf;
    _Float16* bdst = Bs + srow * 32 + shalf;
    const int fr = lane & 15, fq = lane >> 4;
    const _Float16* ard = As + (wr * 64 + fr) * 32 + fq * 8;
    const _Float16* brd = Bs + (wc * 64 + fr) * 32 + fq * 8;
    f32x4 acc[4][4];
#pragma unroll
    for (int i = 0; i < 4; ++i)
#pragma unroll
        for (int j = 0; j < 4; ++j) acc[i][j] = f32x4{0.f, 0.f, 0.f, 0.f};
    for (int kt = 0; kt < KDIM / 32; ++kt) {
        const int k0 = kt * 32;
        const float4* xp = (const float4*)(xsrc + k0);
        const float4 x0 = xp[0], x1 = xp[1], x2 = xp[2], x3 = xp[3];
        const float xv[16] = {x0.x, x0.y, x0.z, x0.w, x1.x, x1.y, x1.z, x1.w,
                              x2.x, x2.y, x2.z, x2.w, x3.x, x3.y, x3.z, x3.w};
        f16x8 a0, a1;
#pragma unroll
        for (int j = 0; j < 8; ++j) { a0[j] = (_Float16)xv[j]; a1[j] = (_Float16)xv[j + 8]; }
        const int g = k0 >> 7;
        const float sf = scp[(size_t)g * NDIM];
        const float zf = zpp[(size_t)g * NDIM];
        const int4* qp = (const int4*)(qsrc + k0);
        const int4 q0 = qp[0], q1 = qp[1], q2 = qp[2], q3 = qp[3];
        const int qv[16] = {q0.x, q0.y, q0.z, q0.w, q1.x, q1.y, q1.z, q1.w,
                            q2.x, q2.y, q2.z, q2.w, q3.x, q3.y, q3.z, q3.w};
        f16x8 w0, w1;
#pragma unroll
        for (int j = 0; j < 8; ++j) {
            w0[j] = (_Float16)((float)qv[j]     * sf + zf);
            w1[j] = (_Float16)((float)qv[j + 8] * sf + zf);
        }
        *(f16x8*)adst = a0; *(f16x8*)(adst + 8) = a1;
        *(f16x8*)bdst = w0; *(f16x8*)(bdst + 8) = w1;
        __syncthreads();
        f16x8 a[4], b[4];
#pragma unroll
        for (int i = 0; i < 4; ++i) a[i] = *(const f16x8*)(ard + i * 16 * 32);
#pragma unroll
        for (int j = 0; j < 4; ++j) b[j] = *(const f16x8*)(brd + j * 16 * 32);
#pragma unroll
        for (int i = 0; i < 4; ++i)
#pragma unroll
            for (int j = 0; j < 4; ++j)
                acc[i][j] = __builtin_amdgcn_mfma_f32_16x16x32_f16(a[i], b[j], acc[i][j], 0, 0, 0);
        __syncthreads();
    }
#pragma unroll
    for (int j = 0; j < 4; ++j) {
        const int n = n0 + wc * 64 + j * 16 + fr;
        const _Float16 bv = (_Float16)Bi[n];
#pragma unroll
        for (int i = 0; i < 4; ++i) {
            const int mbase = m0 + wr * 64 + i * 16 + fq * 4;
#pragma unroll
            for (int r = 0; r < 4; ++r) {
                const _Float16 h = (_Float16)acc[i][j][r] + bv;
                Out[(size_t)(mbase + r) * NDIM + n] = (float)h;
            }
        }
    }
}

extern "C" void kernel_launch(void* const* d_in, const int* in_sizes, int n_in,
                              void* d_out, int out_size, void* d_ws, size_t ws_size,
                              hipStream_t stream) {
    const float* x  = nullptr;
    const int*   q  = nullptr;
    const float* sc = nullptr;
    const float* zp = nullptr;
    const float* bi = nullptr;
    for (int i = 0; i < n_in; ++i) {
        switch (in_sizes[i]) {
            case 33554432: x = (const float*)d_in[i]; break;
            case 45088768: q = (const int*)d_in[i]; break;
            case 352256:   if (!sc) sc = (const float*)d_in[i];
                           else     zp = (const float*)d_in[i];
                           break;
            case 11008:    bi = (const float*)d_in[i]; break;
            default: break;
        }
    }
    if (!x || !q || !sc || !zp || !bi) {
        x  = (const float*)d_in[0];
        q  = (const int*)d_in[1];
        sc = (const float*)d_in[2];
        zp = (const float*)d_in[3];
        bi = (const float*)d_in[4];
    }
    float* out = (float*)d_out;

    if (ws_size >= (size_t)WS_NEED) {
        unsigned int* pq = (unsigned int*)d_ws;
        _Float16*     xh = (_Float16*)((char*)d_ws + PQ_BYTES);
        pack_q<<<5636096 / 256, 256, 0, stream>>>(q, pq);
        cvt_x<<<33554432 / 8 / 256, 256, 0, stream>>>(x, xh);
        wq_gemm_p<<<(NDIM / BN) * (TOKENS / BM), 256, 0, stream>>>(xh, pq, sc, zp, bi, out);
    } else {
        dim3 grid(NDIM / BN, TOKENS / BM);
        wq_gemm_direct<<<grid, dim3(256), 0, stream>>>(x, q, sc, zp, bi, out);
    }
}

// Round 8
// 1139.108 us; speedup vs baseline: 1.0634x; 1.0634x over previous
//
// Round 8: pre-dequant W->fp16 in d_ws + pure fp16 MFMA GEMM with 2-phase double-buffered
// LDS (T3-min), global_load_lds staging with per-lane XOR-swizzled sources, n-fastest XCD
// ordering. Tiered fallback: packed fused path (round 7), then direct (round 5).
#include <hip/hip_runtime.h>
#include <stdint.h>

#define TOKENS 8192
#define KDIM   4096
#define NDIM   11008
#define BM 128
#define BN 128
#define BK 64
#define KT (KDIM / BK)

#define WH_BYTES 90177536ull            // 11008*4096*2
#define XH_BYTES 67108864ull            // 8192*4096*2
#define WS_FULL  (WH_BYTES + XH_BYTES)  // 157286400

#define QWPR 512
#define PQ_BYTES  (45088768u/8u*4u)     // 22544384
#define WS_PACKED ((size_t)PQ_BYTES + XH_BYTES)

typedef _Float16 f16x8 __attribute__((ext_vector_type(8)));
typedef float    f32x4 __attribute__((ext_vector_type(4)));

typedef const __attribute__((address_space(1))) unsigned int* gptr_t;
typedef __attribute__((address_space(3))) unsigned int* lptr_t;

// ---------------- pass 1a: dequant all weights to fp16 (8 per thread) ----------------
__global__ __launch_bounds__(256) void dequant_w(const int* __restrict__ Qw,
                                                 const float* __restrict__ Sc,
                                                 const float* __restrict__ Zp,
                                                 _Float16* __restrict__ Wh) {
    const size_t flat = (size_t)(blockIdx.x * 256 + threadIdx.x) * 8;
    const int o = (int)(flat >> 12);
    const int k = (int)(flat & 4095);
    const int g = k >> 7;
    const float sf = Sc[(size_t)g * NDIM + o];
    const float zf = Zp[(size_t)g * NDIM + o];
    const int4* qp = (const int4*)(Qw + flat);
    const int4 a = qp[0], b = qp[1];
    const int qv[8] = {a.x, a.y, a.z, a.w, b.x, b.y, b.z, b.w};
    f16x8 w;
#pragma unroll
    for (int j = 0; j < 8; ++j) w[j] = (_Float16)((float)qv[j] * sf + zf);
    *(f16x8*)(Wh + flat) = w;
}

// ---------------- pass 1b: x fp32 -> fp16 (exact) ----------------
__global__ __launch_bounds__(256) void cvt_x(const float* __restrict__ x,
                                             _Float16* __restrict__ xh) {
    const size_t idx = (size_t)(blockIdx.x * 256 + threadIdx.x) * 8;
    const float4* p = (const float4*)(x + idx);
    const float4 a = p[0], b = p[1];
    f16x8 o;
    o[0] = (_Float16)a.x; o[1] = (_Float16)a.y; o[2] = (_Float16)a.z; o[3] = (_Float16)a.w;
    o[4] = (_Float16)b.x; o[5] = (_Float16)b.y; o[6] = (_Float16)b.z; o[7] = (_Float16)b.w;
    *(f16x8*)(xh + idx) = o;
}

// ---------------- pass 2 (FULL tier): 2-phase dbuf fp16 GEMM ----------------
// LDS layout per tile row (64 fp16 = 8 x 16B blocks): physical blk = logical ^ (row&7).
// Achieved with LINEAR LDS dest (global_load_lds) + per-lane XOR'd GLOBAL source:
//   lane L of issue i: row=(wid*4+i)*8 + (L>>3), srcblk=(L&7)^(L>>3)  (row&7 == L>>3).
__global__ __launch_bounds__(256, 2)
void wq_gemm2(const _Float16* __restrict__ Xh, const _Float16* __restrict__ Wh,
              const float* __restrict__ Bi, float* __restrict__ Out)
{
    __shared__ __align__(16) _Float16 As[2][BM * BK];   // 2 x 16 KB
    __shared__ __align__(16) _Float16 Bs[2][BN * BK];   // 2 x 16 KB

    const int t    = threadIdx.x;
    const int lane = t & 63;
    const int wid  = t >> 6;
    const int wr   = wid >> 1;                  // 2x2 waves; 64x64 out each
    const int wc   = wid & 1;

    // XCD-bijective, n-fastest (A-tile L2-resident across 86 n-blocks)
    const unsigned int bid = blockIdx.x;
    const unsigned int wg  = (bid & 7u) * 688u + (bid >> 3);
    const int m0 = (int)(wg / 86u) * BM;
    const int n0 = (int)(wg % 86u) * BN;

    // staging source addresses (per-lane, pre-XOR'd)
    const int lrow = lane >> 3;                 // row within 8-row issue slab
    const int lblk = lane & 7;
    const int scol = (lblk ^ lrow) * 8;         // swizzled elem offset within row
    const _Float16* aSrc = Xh + (size_t)(m0 + wid * 32 + lrow) * KDIM + scol;
    const _Float16* bSrc = Wh + (size_t)(n0 + wid * 32 + lrow) * KDIM + scol;

    // fragment read map: row = wseg + i*16 + fr; kblk = kk*4+fq; phys = kblk ^ (fr&7)
    const int fr = lane & 15;
    const int fq = lane >> 4;
    const int fx = fr & 7;
    const int offk0 = ((fq    ) ^ fx) << 3;
    const int offk1 = ((4 + fq) ^ fx) << 3;
    const int arow = wr * 64 + fr;
    const int brow = wc * 64 + fr;

    f32x4 acc[4][4];
#pragma unroll
    for (int i = 0; i < 4; ++i)
#pragma unroll
        for (int j = 0; j < 4; ++j)
            acc[i][j] = f32x4{0.f, 0.f, 0.f, 0.f};

#define STAGE(bufsel, ktv) do {                                                       \
    _Pragma("unroll")                                                                 \
    for (int i_ = 0; i_ < 4; ++i_)                                                    \
        __builtin_amdgcn_global_load_lds(                                             \
            (gptr_t)(const void*)(aSrc + (size_t)i_ * 8 * KDIM + (ktv) * BK),         \
            (lptr_t)(void*)(&As[bufsel][(wid * 4 + i_) * 512]), 16, 0, 0);            \
    _Pragma("unroll")                                                                 \
    for (int i_ = 0; i_ < 4; ++i_)                                                    \
        __builtin_amdgcn_global_load_lds(                                             \
            (gptr_t)(const void*)(bSrc + (size_t)i_ * 8 * KDIM + (ktv) * BK),         \
            (lptr_t)(void*)(&Bs[bufsel][(wid * 4 + i_) * 512]), 16, 0, 0);            \
} while (0)

    STAGE(0, 0);
    __syncthreads();

    int cur = 0;
    for (int kt = 0; kt < KT; ++kt) {
        if (kt + 1 < KT) STAGE(cur ^ 1, kt + 1);   // prefetch in flight across MFMA phase

#pragma unroll
        for (int kk = 0; kk < 2; ++kk) {
            const int offk = kk ? offk1 : offk0;
            f16x8 a[4], b[4];
#pragma unroll
            for (int i = 0; i < 4; ++i)
                a[i] = *(const f16x8*)&As[cur][(arow + i * 16) * BK + offk];
#pragma unroll
            for (int j = 0; j < 4; ++j)
                b[j] = *(const f16x8*)&Bs[cur][(brow + j * 16) * BK + offk];
#pragma unroll
            for (int i = 0; i < 4; ++i)
#pragma unroll
                for (int j = 0; j < 4; ++j)
                    acc[i][j] = __builtin_amdgcn_mfma_f32_16x16x32_f16(a[i], b[j], acc[i][j], 0, 0, 0);
        }

        __syncthreads();   // drains vmcnt(0): prefetched tile complete; reads of cur done
        cur ^= 1;
    }
#undef STAGE

    // epilogue: C/D map col=lane&15, row=(lane>>4)*4+reg; out = f32(f16(acc)+f16(bias))
#pragma unroll
    for (int j = 0; j < 4; ++j) {
        const int n = n0 + wc * 64 + j * 16 + fr;
        const _Float16 bv = (_Float16)Bi[n];
#pragma unroll
        for (int i = 0; i < 4; ++i) {
            const int mbase = m0 + wr * 64 + i * 16 + fq * 4;
#pragma unroll
            for (int r = 0; r < 4; ++r) {
                const _Float16 h = (_Float16)acc[i][j][r] + bv;
                Out[(size_t)(mbase + r) * NDIM + n] = (float)h;
            }
        }
    }
}

// ---------------- middle tier: round-7 packed fused path ----------------
__global__ __launch_bounds__(256) void pack_q(const int* __restrict__ q,
                                              unsigned int* __restrict__ pq) {
    const unsigned int idx = blockIdx.x * 256 + threadIdx.x;
    const int4* p = (const int4*)(q + (size_t)idx * 8);
    const int4 a = p[0], b = p[1];
    unsigned int w = (unsigned int)(a.x & 15)
                   | ((unsigned int)(a.y & 15) << 4)
                   | ((unsigned int)(a.z & 15) << 8)
                   | ((unsigned int)(a.w & 15) << 12)
                   | ((unsigned int)(b.x & 15) << 16)
                   | ((unsigned int)(b.y & 15) << 20)
                   | ((unsigned int)(b.z & 15) << 24)
                   | ((unsigned int)(b.w & 15) << 28);
    pq[idx] = w;
}

__global__ __launch_bounds__(256, 4)
void wq_gemm_p(const _Float16* __restrict__ Xh, const unsigned int* __restrict__ Pq,
               const float* __restrict__ Sc, const float* __restrict__ Zp,
               const float* __restrict__ Bi, float* __restrict__ Out)
{
    __shared__ __align__(16) _Float16 As[BM * BK];
    __shared__ __align__(16) _Float16 Bs[BN * BK];
    const int t = threadIdx.x, lane = t & 63, wid = t >> 6;
    const int wr = wid >> 1, wc = wid & 1;
    const unsigned int bid = blockIdx.x;
    const unsigned int wg  = (bid & 7u) * 688u + (bid >> 3);
    const int m0 = (int)(wg / 86u) * BM;
    const int n0 = (int)(wg % 86u) * BN;
    const int arow = t >> 3, ablk = t & 7;
    const _Float16* asrc = Xh + (size_t)(m0 + arow) * KDIM + ablk * 8;
    const int apos = ((ablk ^ (arow & 7)) << 3);
    _Float16* adst0 = As + arow * BK + apos;
    const int brow = t >> 1, bhalf = t & 1;
    const unsigned int* qsrc = Pq + (size_t)(n0 + brow) * QWPR + bhalf * 4;
    const float* scp = Sc + n0 + brow;
    const float* zpp = Zp + n0 + brow;
    const int bxor = brow & 7;
    _Float16* bdst[4];
#pragma unroll
    for (int d = 0; d < 4; ++d)
        bdst[d] = Bs + brow * BK + (((bhalf * 4 + d) ^ bxor) << 3);
    const int fr = lane & 15, fq = lane >> 4, fxor = fr & 7;
    const int offk0 = ((0 * 4 + fq) ^ fxor) << 3;
    const int offk1 = ((1 * 4 + fq) ^ fxor) << 3;
    f32x4 acc[4][4];
#pragma unroll
    for (int i = 0; i < 4; ++i)
#pragma unroll
        for (int j = 0; j < 4; ++j) acc[i][j] = f32x4{0.f, 0.f, 0.f, 0.f};
    for (int kt = 0; kt < KDIM / BK; ++kt) {
        f16x8 av[4];
#pragma unroll
        for (int rr = 0; rr < 4; ++rr)
            av[rr] = *(const f16x8*)(asrc + (size_t)rr * 32 * KDIM + kt * BK);
        const int g = kt >> 1;
        const float sf = scp[(size_t)g * NDIM];
        const float zf = zpp[(size_t)g * NDIM];
        const uint4 pw = *(const uint4*)(qsrc + kt * 8);
        const unsigned int pv[4] = {pw.x, pw.y, pw.z, pw.w};
        f16x8 w[4];
#pragma unroll
        for (int d = 0; d < 4; ++d)
#pragma unroll
            for (int j = 0; j < 8; ++j)
                w[d][j] = (_Float16)((float)((pv[d] >> (4 * j)) & 15u) * sf + zf);
#pragma unroll
        for (int rr = 0; rr < 4; ++rr) *(f16x8*)(adst0 + rr * 32 * BK) = av[rr];
#pragma unroll
        for (int d = 0; d < 4; ++d) *(f16x8*)bdst[d] = w[d];
        __syncthreads();
#pragma unroll
        for (int kk = 0; kk < 2; ++kk) {
            const int offk = kk ? offk1 : offk0;
            f16x8 a[4], b[4];
#pragma unroll
            for (int i = 0; i < 4; ++i)
                a[i] = *(const f16x8*)(As + (wr * 64 + i * 16 + fr) * BK + offk);
#pragma unroll
            for (int j = 0; j < 4; ++j)
                b[j] = *(const f16x8*)(Bs + (wc * 64 + j * 16 + fr) * BK + offk);
#pragma unroll
            for (int i = 0; i < 4; ++i)
#pragma unroll
                for (int j = 0; j < 4; ++j)
                    acc[i][j] = __builtin_amdgcn_mfma_f32_16x16x32_f16(a[i], b[j], acc[i][j], 0, 0, 0);
        }
        __syncthreads();
    }
#pragma unroll
    for (int j = 0; j < 4; ++j) {
        const int n = n0 + wc * 64 + j * 16 + fr;
        const _Float16 bv = (_Float16)Bi[n];
#pragma unroll
        for (int i = 0; i < 4; ++i) {
            const int mbase = m0 + wr * 64 + i * 16 + fq * 4;
#pragma unroll
            for (int r = 0; r < 4; ++r) {
                const _Float16 h = (_Float16)acc[i][j][r] + bv;
                Out[(size_t)(mbase + r) * NDIM + n] = (float)h;
            }
        }
    }
}

// ---------------- last tier: round-5 direct kernel ----------------
__global__ __launch_bounds__(256, 2)
void wq_gemm_direct(const float* __restrict__ X,  const int* __restrict__ Qw,
                    const float* __restrict__ Sc, const float* __restrict__ Zp,
                    const float* __restrict__ Bi, float* __restrict__ Out)
{
    __shared__ __align__(16) _Float16 As[BM * 32];
    __shared__ __align__(16) _Float16 Bs[BN * 32];
    const int t = threadIdx.x, lane = t & 63, wid = t >> 6;
    const int wr = wid >> 1, wc = wid & 1;
    const int n0 = blockIdx.x * BN, m0 = blockIdx.y * BM;
    const int srow = t >> 1, shalf = (t & 1) << 4;
    const float* xsrc = X + (size_t)(m0 + srow) * KDIM + shalf;
    const int*   qsrc = Qw + (size_t)(n0 + srow) * KDIM + shalf;
    const float* scp = Sc + n0 + srow;
    const float* zpp = Zp + n0 + srow;
    _Float16* adst = As + srow * 32 + shalf;
    _Float16* bdst = Bs + srow * 32 + shalf;
    const int fr = lane & 15, fq = lane >> 4;
    const _Float16* ard = As + (wr * 64 + fr) * 32 + fq * 8;
    const _Float16* brd = Bs + (wc * 64 + fr) * 32 + fq * 8;
    f32x4 acc[4][4];
#pragma unroll
    for (int i = 0; i < 4; ++i)
#pragma unroll
        for (int j = 0; j < 4; ++j) acc[i][j] = f32x4{0.f, 0.f, 0.f, 0.f};
    for (int kt = 0; kt < KDIM / 32; ++kt) {
        const int k0 = kt * 32;
        const float4* xp = (const float4*)(xsrc + k0);
        const float4 x0 = xp[0], x1 = xp[1], x2 = xp[2], x3 = xp[3];
        const float xv[16] = {x0.x, x0.y, x0.z, x0.w, x1.x, x1.y, x1.z, x1.w,
                              x2.x, x2.y, x2.z, x2.w, x3.x, x3.y, x3.z, x3.w};
        f16x8 a0, a1;
#pragma unroll
        for (int j = 0; j < 8; ++j) { a0[j] = (_Float16)xv[j]; a1[j] = (_Float16)xv[j + 8]; }
        const int g = k0 >> 7;
        const float sf = scp[(size_t)g * NDIM];
        const float zf = zpp[(size_t)g * NDIM];
        const int4* qp = (const int4*)(qsrc + k0);
        const int4 q0 = qp[0], q1 = qp[1], q2 = qp[2], q3 = qp[3];
        const int qv[16] = {q0.x, q0.y, q0.z, q0.w, q1.x, q1.y, q1.z, q1.w,
                            q2.x, q2.y, q2.z, q2.w, q3.x, q3.y, q3.z, q3.w};
        f16x8 w0, w1;
#pragma unroll
        for (int j = 0; j < 8; ++j) {
            w0[j] = (_Float16)((float)qv[j]     * sf + zf);
            w1[j] = (_Float16)((float)qv[j + 8] * sf + zf);
        }
        *(f16x8*)adst = a0; *(f16x8*)(adst + 8) = a1;
        *(f16x8*)bdst = w0; *(f16x8*)(bdst + 8) = w1;
        __syncthreads();
        f16x8 a[4], b[4];
#pragma unroll
        for (int i = 0; i < 4; ++i) a[i] = *(const f16x8*)(ard + i * 16 * 32);
#pragma unroll
        for (int j = 0; j < 4; ++j) b[j] = *(const f16x8*)(brd + j * 16 * 32);
#pragma unroll
        for (int i = 0; i < 4; ++i)
#pragma unroll
            for (int j = 0; j < 4; ++j)
                acc[i][j] = __builtin_amdgcn_mfma_f32_16x16x32_f16(a[i], b[j], acc[i][j], 0, 0, 0);
        __syncthreads();
    }
#pragma unroll
    for (int j = 0; j < 4; ++j) {
        const int n = n0 + wc * 64 + j * 16 + fr;
        const _Float16 bv = (_Float16)Bi[n];
#pragma unroll
        for (int i = 0; i < 4; ++i) {
            const int mbase = m0 + wr * 64 + i * 16 + fq * 4;
#pragma unroll
            for (int r = 0; r < 4; ++r) {
                const _Float16 h = (_Float16)acc[i][j][r] + bv;
                Out[(size_t)(mbase + r) * NDIM + n] = (float)h;
            }
        }
    }
}

extern "C" void kernel_launch(void* const* d_in, const int* in_sizes, int n_in,
                              void* d_out, int out_size, void* d_ws, size_t ws_size,
                              hipStream_t stream) {
    const float* x  = nullptr;
    const int*   q  = nullptr;
    const float* sc = nullptr;
    const float* zp = nullptr;
    const float* bi = nullptr;
    for (int i = 0; i < n_in; ++i) {
        switch (in_sizes[i]) {
            case 33554432: x = (const float*)d_in[i]; break;
            case 45088768: q = (const int*)d_in[i]; break;
            case 352256:   if (!sc) sc = (const float*)d_in[i];
                           else     zp = (const float*)d_in[i];
                           break;
            case 11008:    bi = (const float*)d_in[i]; break;
            default: break;
        }
    }
    if (!x || !q || !sc || !zp || !bi) {
        x  = (const float*)d_in[0];
        q  = (const int*)d_in[1];
        sc = (const float*)d_in[2];
        zp = (const float*)d_in[3];
        bi = (const float*)d_in[4];
    }
    float* out = (float*)d_out;

    if (ws_size >= (size_t)WS_FULL) {
        _Float16* wh = (_Float16*)d_ws;
        _Float16* xh = (_Float16*)((char*)d_ws + WH_BYTES);
        dequant_w<<<45088768 / 8 / 256, 256, 0, stream>>>(q, sc, zp, wh);
        cvt_x<<<33554432 / 8 / 256, 256, 0, stream>>>(x, xh);
        wq_gemm2<<<(NDIM / BN) * (TOKENS / BM), 256, 0, stream>>>(xh, wh, bi, out);
    } else if (ws_size >= WS_PACKED) {
        unsigned int* pq = (unsigned int*)d_ws;
        _Float16*     xh = (_Float16*)((char*)d_ws + PQ_BYTES);
        pack_q<<<5636096 / 256, 256, 0, stream>>>(q, pq);
        cvt_x<<<33554432 / 8 / 256, 256, 0, stream>>>(x, xh);
        wq_gemm_p<<<(NDIM / BN) * (TOKENS / BM), 256, 0, stream>>>(xh, pq, sc, zp, bi, out);
    } else {
        dim3 grid(NDIM / BN, TOKENS / BM);
        wq_gemm_direct<<<grid, dim3(256), 0, stream>>>(x, q, sc, zp, bi, out);
    }
}

// Round 9
// 1055.980 us; speedup vs baseline: 1.1471x; 1.0787x over previous
//
// Round 9: packed-q fused dequant + BK=32 double-buffered pipeline (T14 split: prefetch
// A via global_load_lds + q-to-regs BEFORE MFMA phase, dequant+ds_write after, 1 barrier
// per K-step), XOR-swizzled LDS (blk ^ ((row>>1)&3)), n-fastest XCD order, NT stores.
#include <hip/hip_runtime.h>
#include <stdint.h>

#define TOKENS 8192
#define KDIM   4096
#define NDIM   11008
#define BM 128
#define BN 128
#define BK 32
#define KT (KDIM / BK)              // 128
#define QWPR 512                    // packed dwords per q row
#define PQ_BYTES (45088768u/8u*4u)  // 22544384
#define XH_BYTES (33554432ull*2ull) // 67108864
#define WS_PACKED ((size_t)PQ_BYTES + XH_BYTES)

typedef _Float16 f16x8 __attribute__((ext_vector_type(8)));
typedef float    f32x4 __attribute__((ext_vector_type(4)));

typedef const __attribute__((address_space(1))) unsigned int* gptr_t;
typedef __attribute__((address_space(3))) unsigned int* lptr_t;

// ---------------- pass 1a: pack 8 int32 (4-bit values) -> 1 dword ----------------
__global__ __launch_bounds__(256) void pack_q(const int* __restrict__ q,
                                              unsigned int* __restrict__ pq) {
    const unsigned int idx = blockIdx.x * 256 + threadIdx.x;
    const int4* p = (const int4*)(q + (size_t)idx * 8);
    const int4 a = p[0], b = p[1];
    unsigned int w = (unsigned int)(a.x & 15)
                   | ((unsigned int)(a.y & 15) << 4)
                   | ((unsigned int)(a.z & 15) << 8)
                   | ((unsigned int)(a.w & 15) << 12)
                   | ((unsigned int)(b.x & 15) << 16)
                   | ((unsigned int)(b.y & 15) << 20)
                   | ((unsigned int)(b.z & 15) << 24)
                   | ((unsigned int)(b.w & 15) << 28);
    pq[idx] = w;
}

// ---------------- pass 1b: x fp32 -> fp16 (exact: data is fp16-valued) ----------------
__global__ __launch_bounds__(256) void cvt_x(const float* __restrict__ x,
                                             _Float16* __restrict__ xh) {
    const size_t idx = (size_t)(blockIdx.x * 256 + threadIdx.x) * 8;
    const float4* p = (const float4*)(x + idx);
    const float4 a = p[0], b = p[1];
    f16x8 o;
    o[0] = (_Float16)a.x; o[1] = (_Float16)a.y; o[2] = (_Float16)a.z; o[3] = (_Float16)a.w;
    o[4] = (_Float16)b.x; o[5] = (_Float16)b.y; o[6] = (_Float16)b.z; o[7] = (_Float16)b.w;
    *(f16x8*)(xh + idx) = o;
}

// ---------------- pass 2: dbuf fused-dequant GEMM ----------------
// LDS row = 32 fp16 = 4 x 16B blocks; physical blk = logical ^ ((row>>1)&3).
// A staged by global_load_lds (linear dest) with per-lane pre-XOR'd global source.
__global__ __launch_bounds__(256, 4)
void wq_gemm_db(const _Float16* __restrict__ Xh, const unsigned int* __restrict__ Pq,
                const float* __restrict__ Sc, const float* __restrict__ Zp,
                const float* __restrict__ Bi, float* __restrict__ Out)
{
    __shared__ __align__(16) _Float16 As[2][BM * BK];   // 2 x 8 KB
    __shared__ __align__(16) _Float16 Bs[2][BN * BK];   // 2 x 8 KB

    const int t    = threadIdx.x;
    const int lane = t & 63;
    const int wid  = t >> 6;
    const int wr   = wid >> 1;                  // 2x2 waves; 64x64 out each
    const int wc   = wid & 1;

    // XCD-bijective, n-fastest (A-tile L2-resident across its 86 n-blocks)
    const unsigned int bid = blockIdx.x;
    const unsigned int wg  = (bid & 7u) * 688u + (bid >> 3);
    const int m0 = (int)(wg / 86u) * BM;
    const int n0 = (int)(wg % 86u) * BN;

    // ---- A staging: 2 gload_lds issues/wave; lane L -> row issue*16+(L>>2),
    //      src col-block (L&3)^((L>>3)&3)  (== XOR of (row>>1)&3 since row>>1 ≡ L>>3 mod 4)
    const int alrow = lane >> 2;
    const int ablk  = (lane & 3) ^ ((lane >> 3) & 3);
    const _Float16* aSrc = Xh + (size_t)(m0 + wid * 32 + alrow) * KDIM + ablk * 8;

    // ---- B staging: thread t -> row t>>1, 2 packed dwords (16 nibbles) ----
    const int brow  = t >> 1;
    const int bhalf = t & 1;
    const unsigned int* qsrc = Pq + (size_t)(n0 + brow) * QWPR + bhalf * 2;
    const float* scp = Sc + n0 + brow;
    const float* zpp = Zp + n0 + brow;
    const int bx = (brow >> 1) & 3;
    const int bofs0 = brow * BK + (((bhalf * 2)     ^ bx) << 3);
    const int bofs1 = brow * BK + (((bhalf * 2 + 1) ^ bx) << 3);

    // ---- fragment read map: row = seg + i*16 + fr; blk = fq; phys = fq ^ ((fr>>1)&3)
    const int fr = lane & 15;
    const int fq = lane >> 4;
    const int offk = ((fq ^ ((fr >> 1) & 3)) << 3);
    const int arow = wr * 64 + fr;
    const int brow2 = wc * 64 + fr;

    f32x4 acc[4][4];
#pragma unroll
    for (int i = 0; i < 4; ++i)
#pragma unroll
        for (int j = 0; j < 4; ++j)
            acc[i][j] = f32x4{0.f, 0.f, 0.f, 0.f};

#define STAGE_A(bufsel, ktv) do {                                                     \
    _Pragma("unroll")                                                                 \
    for (int i_ = 0; i_ < 2; ++i_)                                                    \
        __builtin_amdgcn_global_load_lds(                                             \
            (gptr_t)(const void*)(aSrc + (size_t)i_ * 16 * KDIM + (ktv) * BK),        \
            (lptr_t)(void*)(&As[bufsel][wid * 1024 + i_ * 512]), 16, 0, 0);           \
} while (0)

#define DEQ_WRITE(bufsel, qv) do {                                                    \
    const int g_ = 0; (void)g_;                                                       \
    f16x8 w0_, w1_;                                                                   \
    _Pragma("unroll")                                                                 \
    for (int j_ = 0; j_ < 8; ++j_) {                                                  \
        w0_[j_] = (_Float16)((float)((qv.x >> (4 * j_)) & 15u) * sf + zf);            \
        w1_[j_] = (_Float16)((float)((qv.y >> (4 * j_)) & 15u) * sf + zf);            \
    }                                                                                 \
    *(f16x8*)&Bs[bufsel][bofs0] = w0_;                                                \
    *(f16x8*)&Bs[bufsel][bofs1] = w1_;                                                \
} while (0)

    // prologue: tile 0
    STAGE_A(0, 0);
    {
        const float sf = scp[0];           // group 0
        const float zf = zpp[0];
        const uint2 qv = *(const uint2*)(qsrc);
        DEQ_WRITE(0, qv);
    }
    __syncthreads();

    int cur = 0;
    for (int kt = 0; kt < KT; ++kt) {
        const int ktn = (kt + 1 < KT) ? kt + 1 : kt;   // clamp: last iter redundant

        // prefetch next tile: A -> LDS (async), q -> regs
        STAGE_A(cur ^ 1, ktn);
        const uint2 qv = *(const uint2*)(qsrc + ktn * 4);
        const int g = ktn >> 2;                        // 4 K-steps per 128-group
        const float sf = scp[(size_t)g * NDIM];
        const float zf = zpp[(size_t)g * NDIM];

        // compute on current tile
        f16x8 a[4], b[4];
#pragma unroll
        for (int i = 0; i < 4; ++i)
            a[i] = *(const f16x8*)&As[cur][(arow + i * 16) * BK + offk];
#pragma unroll
        for (int j = 0; j < 4; ++j)
            b[j] = *(const f16x8*)&Bs[cur][(brow2 + j * 16) * BK + offk];
#pragma unroll
        for (int i = 0; i < 4; ++i)
#pragma unroll
            for (int j = 0; j < 4; ++j)
                acc[i][j] = __builtin_amdgcn_mfma_f32_16x16x32_f16(a[i], b[j], acc[i][j], 0, 0, 0);

        // dequant + stage B for next tile (writes go to the buffer nobody reads)
        DEQ_WRITE(cur ^ 1, qv);

        __syncthreads();   // drains vmcnt(0): A prefetch landed; all reads of cur done
        cur ^= 1;
    }
#undef STAGE_A
#undef DEQ_WRITE

    // epilogue: C/D map col=lane&15, row=(lane>>4)*4+reg; out = f32(f16(acc)+f16(bias));
    // nontemporal stores keep Out from evicting the L2-resident A-tile.
#pragma unroll
    for (int j = 0; j < 4; ++j) {
        const int n = n0 + wc * 64 + j * 16 + fr;
        const _Float16 bv = (_Float16)Bi[n];
#pragma unroll
        for (int i = 0; i < 4; ++i) {
            const int mbase = m0 + wr * 64 + i * 16 + fq * 4;
#pragma unroll
            for (int r = 0; r < 4; ++r) {
                const _Float16 h = (_Float16)acc[i][j][r] + bv;
                __builtin_nontemporal_store((float)h, &Out[(size_t)(mbase + r) * NDIM + n]);
            }
        }
    }
}

// ---------------- fallback: round-5 direct kernel (no workspace) ----------------
__global__ __launch_bounds__(256, 2)
void wq_gemm_direct(const float* __restrict__ X,  const int* __restrict__ Qw,
                    const float* __restrict__ Sc, const float* __restrict__ Zp,
                    const float* __restrict__ Bi, float* __restrict__ Out)
{
    __shared__ __align__(16) _Float16 As[BM * 32];
    __shared__ __align__(16) _Float16 Bs[BN * 32];
    const int t = threadIdx.x, lane = t & 63, wid = t >> 6;
    const int wr = wid >> 1, wc = wid & 1;
    const int n0 = blockIdx.x * BN, m0 = blockIdx.y * BM;
    const int srow = t >> 1, shalf = (t & 1) << 4;
    const float* xsrc = X + (size_t)(m0 + srow) * KDIM + shalf;
    const int*   qsrc = Qw + (size_t)(n0 + srow) * KDIM + shalf;
    const float* scp = Sc + n0 + srow;
    const float* zpp = Zp + n0 + srow;
    _Float16* adst = As + srow * 32 + shalf;
    _Float16* bdst = Bs + srow * 32 + shalf;
    const int fr = lane & 15, fq = lane >> 4;
    const _Float16* ard = As + (wr * 64 + fr) * 32 + fq * 8;
    const _Float16* brd = Bs + (wc * 64 + fr) * 32 + fq * 8;
    f32x4 acc[4][4];
#pragma unroll
    for (int i = 0; i < 4; ++i)
#pragma unroll
        for (int j = 0; j < 4; ++j) acc[i][j] = f32x4{0.f, 0.f, 0.f, 0.f};
    for (int kt = 0; kt < KDIM / 32; ++kt) {
        const int k0 = kt * 32;
        const float4* xp = (const float4*)(xsrc + k0);
        const float4 x0 = xp[0], x1 = xp[1], x2 = xp[2], x3 = xp[3];
        const float xv[16] = {x0.x, x0.y, x0.z, x0.w, x1.x, x1.y, x1.z, x1.w,
                              x2.x, x2.y, x2.z, x2.w, x3.x, x3.y, x3.z, x3.w};
        f16x8 a0, a1;
#pragma unroll
        for (int j = 0; j < 8; ++j) { a0[j] = (_Float16)xv[j]; a1[j] = (_Float16)xv[j + 8]; }
        const int g = k0 >> 7;
        const float sf = scp[(size_t)g * NDIM];
        const float zf = zpp[(size_t)g * NDIM];
        const int4* qp = (const int4*)(qsrc + k0);
        const int4 q0 = qp[0], q1 = qp[1], q2 = qp[2], q3 = qp[3];
        const int qv[16] = {q0.x, q0.y, q0.z, q0.w, q1.x, q1.y, q1.z, q1.w,
                            q2.x, q2.y, q2.z, q2.w, q3.x, q3.y, q3.z, q3.w};
        f16x8 w0, w1;
#pragma unroll
        for (int j = 0; j < 8; ++j) {
            w0[j] = (_Float16)((float)qv[j]     * sf + zf);
            w1[j] = (_Float16)((float)qv[j + 8] * sf + zf);
        }
        *(f16x8*)adst = a0; *(f16x8*)(adst + 8) = a1;
        *(f16x8*)bdst = w0; *(f16x8*)(bdst + 8) = w1;
        __syncthreads();
        f16x8 a[4], b[4];
#pragma unroll
        for (int i = 0; i < 4; ++i) a[i] = *(const f16x8*)(ard + i * 16 * 32);
#pragma unroll
        for (int j = 0; j < 4; ++j) b[j] = *(const f16x8*)(brd + j * 16 * 32);
#pragma unroll
        for (int i = 0; i < 4; ++i)
#pragma unroll
            for (int j = 0; j < 4; ++j)
                acc[i][j] = __builtin_amdgcn_mfma_f32_16x16x32_f16(a[i], b[j], acc[i][j], 0, 0, 0);
        __syncthreads();
    }
#pragma unroll
    for (int j = 0; j < 4; ++j) {
        const int n = n0 + wc * 64 + j * 16 + fr;
        const _Float16 bv = (_Float16)Bi[n];
#pragma unroll
        for (int i = 0; i < 4; ++i) {
            const int mbase = m0 + wr * 64 + i * 16 + fq * 4;
#pragma unroll
            for (int r = 0; r < 4; ++r) {
                const _Float16 h = (_Float16)acc[i][j][r] + bv;
                Out[(size_t)(mbase + r) * NDIM + n] = (float)h;
            }
        }
    }
}

extern "C" void kernel_launch(void* const* d_in, const int* in_sizes, int n_in,
                              void* d_out, int out_size, void* d_ws, size_t ws_size,
                              hipStream_t stream) {
    const float* x  = nullptr;
    const int*   q  = nullptr;
    const float* sc = nullptr;
    const float* zp = nullptr;
    const float* bi = nullptr;
    for (int i = 0; i < n_in; ++i) {
        switch (in_sizes[i]) {
            case 33554432: x = (const float*)d_in[i]; break;
            case 45088768: q = (const int*)d_in[i]; break;
            case 352256:   if (!sc) sc = (const float*)d_in[i];
                           else     zp = (const float*)d_in[i];
                           break;
            case 11008:    bi = (const float*)d_in[i]; break;
            default: break;
        }
    }
    if (!x || !q || !sc || !zp || !bi) {
        x  = (const float*)d_in[0];
        q  = (const int*)d_in[1];
        sc = (const float*)d_in[2];
        zp = (const float*)d_in[3];
        bi = (const float*)d_in[4];
    }
    float* out = (float*)d_out;

    if (ws_size >= WS_PACKED) {
        unsigned int* pq = (unsigned int*)d_ws;
        _Float16*     xh = (_Float16*)((char*)d_ws + PQ_BYTES);
        pack_q<<<5636096 / 256, 256, 0, stream>>>(q, pq);
        cvt_x<<<33554432 / 8 / 256, 256, 0, stream>>>(x, xh);
        wq_gemm_db<<<(NDIM / BN) * (TOKENS / BM), 256, 0, stream>>>(xh, pq, sc, zp, bi, out);
    } else {
        dim3 grid(NDIM / BN, TOKENS / BM);
        wq_gemm_direct<<<grid, dim3(256), 0, stream>>>(x, q, sc, zp, bi, out);
    }
}

// Round 10
// 881.762 us; speedup vs baseline: 1.3738x; 1.1976x over previous
//
// Round 10: 256x256xBK64 8-wave GEMM (per-wave 128x64, B-frags reg-cached), dbuf LDS 128KB,
// one barrier/K-tile with loads issued at iter start (structural counted-vmcnt), pk-magic
// fused dequant (permuted nibble pack), XOR swizzle, n-fastest XCD order, NT stores.
#include <hip/hip_runtime.h>
#include <stdint.h>

#define TOKENS 8192
#define KDIM   4096
#define NDIM   11008
#define BM 256
#define BN 256
#define BK 64
#define KTILES (KDIM / BK)          // 64
#define QWPR 512                    // packed dwords per q row
#define PQ_BYTES (45088768u/8u*4u)  // 22544384
#define XH_BYTES (33554432ull*2ull) // 67108864
#define WS_PACKED ((size_t)PQ_BYTES + XH_BYTES)

typedef _Float16 f16x8 __attribute__((ext_vector_type(8)));
typedef _Float16 f16x2 __attribute__((ext_vector_type(2)));
typedef float    f32x4 __attribute__((ext_vector_type(4)));

typedef const __attribute__((address_space(1))) unsigned int* gptr_t;
typedef __attribute__((address_space(3))) unsigned int* lptr_t;

// ---- pass 1a: pack 8 int32 nibbles -> 1 dword, PERMUTED [k0,k2,k4,k6,k1,k3,k5,k7]
// so that ((d>>4i)&0x000F000F)|0x64006400 = fp16 pair (1024+k_{2i}, 1024+k_{2i+1}).
__global__ __launch_bounds__(256) void pack_q(const int* __restrict__ q,
                                              unsigned int* __restrict__ pq) {
    const unsigned int idx = blockIdx.x * 256 + threadIdx.x;
    const int4* p = (const int4*)(q + (size_t)idx * 8);
    const int4 a = p[0], b = p[1];   // a=(k0..k3), b=(k4..k7)
    unsigned int w = (unsigned int)(a.x & 15)
                   | ((unsigned int)(a.z & 15) << 4)
                   | ((unsigned int)(b.x & 15) << 8)
                   | ((unsigned int)(b.z & 15) << 12)
                   | ((unsigned int)(a.y & 15) << 16)
                   | ((unsigned int)(a.w & 15) << 20)
                   | ((unsigned int)(b.y & 15) << 24)
                   | ((unsigned int)(b.w & 15) << 28);
    pq[idx] = w;
}

// ---- pass 1b: x fp32 -> fp16 (exact: data is fp16-valued) ----
__global__ __launch_bounds__(256) void cvt_x(const float* __restrict__ x,
                                             _Float16* __restrict__ xh) {
    const size_t idx = (size_t)(blockIdx.x * 256 + threadIdx.x) * 8;
    const float4* p = (const float4*)(x + idx);
    const float4 a = p[0], b = p[1];
    f16x8 o;
    o[0] = (_Float16)a.x; o[1] = (_Float16)a.y; o[2] = (_Float16)a.z; o[3] = (_Float16)a.w;
    o[4] = (_Float16)b.x; o[5] = (_Float16)b.y; o[6] = (_Float16)b.z; o[7] = (_Float16)b.w;
    *(f16x8*)(xh + idx) = o;
}

// ---- pass 2: 256^2 8-wave fused-dequant GEMM ----
// LDS row = 64 fp16 = 8 x 16B blocks; physical blk = logical ^ (row & 7).
// A: global_load_lds, linear dest, XOR'd source (m173). B: pk-dequant + swizzled ds_write.
__global__ __launch_bounds__(512, 2)
void wq_gemm_8w(const _Float16* __restrict__ Xh, const unsigned int* __restrict__ Pq,
                const float* __restrict__ Sc, const float* __restrict__ Zp,
                const float* __restrict__ Bi, float* __restrict__ Out)
{
    __shared__ __align__(16) _Float16 As[2][BM * BK];   // 2 x 32 KB
    __shared__ __align__(16) _Float16 Bs[2][BN * BK];   // 2 x 32 KB

    const int t    = threadIdx.x;
    const int lane = t & 63;
    const int wid  = t >> 6;        // 0..7
    const int wmr  = wid >> 2;      // 0..1 : wave owns rows wmr*128..+128
    const int wnc  = wid & 3;       // 0..3 : cols wnc*64..+64

    // XCD-bijective, n-fastest (1376 = 8*172; 172 = 4 full m-rows of 43)
    const unsigned int bid = blockIdx.x;
    const unsigned int wg  = (bid & 7u) * 172u + (bid >> 3);
    const int m0 = (int)(wg / 43u) * BM;
    const int n0 = (int)(wg % 43u) * BN;

    // A staging: 4 issues; issue i covers rows i*64 + wid*8 + (lane>>3), blk lane&7.
    // LDS dest linear (base + lane*16B); source pre-XOR'd.
    const int alr = lane >> 3;
    const int alb = lane & 7;
    const _Float16* aSrc = Xh + (size_t)(m0 + wid * 8 + alr) * KDIM + ((alb ^ alr) << 3);

    // B staging: row br = t>>1 (0..255), half bh = t&1 (4 packed dwords = 32 nibbles)
    const int br = t >> 1;
    const int bh = t & 1;
    const unsigned int* qsrc = Pq + (size_t)(n0 + br) * QWPR + bh * 4;
    const float* scp = Sc + n0 + br;
    const float* zpp = Zp + n0 + br;
    const int brx = br & 7;

    // fragment read map: row*64 + ((kh*4+fq)^ (fr&7))*8
    const int fr = lane & 15;
    const int fq = lane >> 4;       // 0..3
    const int fx = fr & 7;

    f32x4 acc[8][4];
#pragma unroll
    for (int i = 0; i < 8; ++i)
#pragma unroll
        for (int j = 0; j < 4; ++j)
            acc[i][j] = f32x4{0.f, 0.f, 0.f, 0.f};

    const f16x2 k1024 = {(_Float16)1024.0f, (_Float16)1024.0f};

#define A_STAGE(buf, ktv) do {                                                        \
    _Pragma("unroll")                                                                 \
    for (int i_ = 0; i_ < 4; ++i_)                                                    \
        __builtin_amdgcn_global_load_lds(                                             \
            (gptr_t)(const void*)(aSrc + (size_t)i_ * 64 * KDIM + (ktv) * BK),        \
            (lptr_t)(void*)(&As[buf][i_ * 4096 + wid * 512]), 16, 0, 0);              \
} while (0)

#define DEQ_STORE(buf, qvv, s2v, z2v) do {                                            \
    _Pragma("unroll")                                                                 \
    for (int d_ = 0; d_ < 4; ++d_) {                                                  \
        const unsigned int dw_ = ((const unsigned int*)&(qvv))[d_];                   \
        unsigned int o_[4];                                                           \
        _Pragma("unroll")                                                             \
        for (int p_ = 0; p_ < 4; ++p_) {                                              \
            unsigned int u_ = ((dw_ >> (4 * p_)) & 0x000F000Fu) | 0x64006400u;        \
            f16x2 h_ = __builtin_bit_cast(f16x2, u_);                                 \
            f16x2 q_ = h_ - k1024;                                                    \
            f16x2 w_ = q_ * (s2v) + (z2v);                                            \
            o_[p_] = __builtin_bit_cast(unsigned int, w_);                            \
        }                                                                             \
        const int kb_ = (bh * 4 + d_) ^ brx;                                          \
        *(uint4*)&Bs[buf][br * 64 + kb_ * 8] = uint4{o_[0], o_[1], o_[2], o_[3]};     \
    }                                                                                 \
} while (0)

    // prologue: tile 0
    A_STAGE(0, 0);
    {
        const float sf = scp[0];
        const float zf = zpp[0];
        const f16x2 s2 = {(_Float16)sf, (_Float16)sf};
        const f16x2 z2 = {(_Float16)zf, (_Float16)zf};
        const uint4 qv = *(const uint4*)(qsrc);
        DEQ_STORE(0, qv, s2, z2);
    }
    __syncthreads();

    int cur = 0;
    for (int kt = 0; kt < KTILES; ++kt) {
        const int ktn = (kt + 1 < KTILES) ? kt + 1 : kt;  // last iter: redundant, harmless

        // issue ALL next-tile loads up front; drained by the end-of-iter barrier
        A_STAGE(cur ^ 1, ktn);
        const uint4 qn = *(const uint4*)(qsrc + ktn * 8);
        const int g = ktn >> 1;
        const float sf = scp[(size_t)g * NDIM];
        const float zf = zpp[(size_t)g * NDIM];

        // cache all 8 B-fragments (4 n x 2 k-halves) once
        f16x8 bc[4][2];
#pragma unroll
        for (int j = 0; j < 4; ++j)
#pragma unroll
            for (int kh = 0; kh < 2; ++kh)
                bc[j][kh] = *(const f16x8*)&Bs[cur][(wnc * 64 + j * 16 + fr) * 64 +
                                                    (((kh << 2) | fq) ^ fx) * 8];

        // 4 phases over m-pairs: 16 MFMA each
#pragma unroll
        for (int p = 0; p < 4; ++p) {
            f16x8 a[2][2];
#pragma unroll
            for (int ii = 0; ii < 2; ++ii)
#pragma unroll
                for (int kh = 0; kh < 2; ++kh)
                    a[ii][kh] = *(const f16x8*)&As[cur][(wmr * 128 + (p * 2 + ii) * 16 + fr) * 64 +
                                                        (((kh << 2) | fq) ^ fx) * 8];
            __builtin_amdgcn_s_setprio(1);
#pragma unroll
            for (int ii = 0; ii < 2; ++ii)
#pragma unroll
                for (int j = 0; j < 4; ++j) {
                    acc[p * 2 + ii][j] = __builtin_amdgcn_mfma_f32_16x16x32_f16(
                        a[ii][0], bc[j][0], acc[p * 2 + ii][j], 0, 0, 0);
                    acc[p * 2 + ii][j] = __builtin_amdgcn_mfma_f32_16x16x32_f16(
                        a[ii][1], bc[j][1], acc[p * 2 + ii][j], 0, 0, 0);
                }
            __builtin_amdgcn_s_setprio(0);
        }

        // dequant next tile into the other buffer (compiler waits qn's vmcnt itself)
        {
            const f16x2 s2 = {(_Float16)sf, (_Float16)sf};
            const f16x2 z2 = {(_Float16)zf, (_Float16)zf};
            DEQ_STORE(cur ^ 1, qn, s2, z2);
        }

        __syncthreads();
        cur ^= 1;
    }
#undef A_STAGE
#undef DEQ_STORE

    // epilogue: C/D map col=lane&15, row=(lane>>4)*4+reg; out = f32(f16(acc)+f16(bias))
#pragma unroll
    for (int j = 0; j < 4; ++j) {
        const int n = n0 + wnc * 64 + j * 16 + fr;
        const _Float16 bv = (_Float16)Bi[n];
#pragma unroll
        for (int im = 0; im < 8; ++im) {
            const int mbase = m0 + wmr * 128 + im * 16 + fq * 4;
#pragma unroll
            for (int r = 0; r < 4; ++r) {
                const _Float16 h = (_Float16)acc[im][j][r] + bv;
                __builtin_nontemporal_store((float)h, &Out[(size_t)(mbase + r) * NDIM + n]);
            }
        }
    }
}

// ---------------- fallback: round-5 direct kernel (no workspace) ----------------
__global__ __launch_bounds__(256, 2)
void wq_gemm_direct(const float* __restrict__ X,  const int* __restrict__ Qw,
                    const float* __restrict__ Sc, const float* __restrict__ Zp,
                    const float* __restrict__ Bi, float* __restrict__ Out)
{
    __shared__ __align__(16) _Float16 As[128 * 32];
    __shared__ __align__(16) _Float16 Bs[128 * 32];
    const int t = threadIdx.x, lane = t & 63, wid = t >> 6;
    const int wr = wid >> 1, wc = wid & 1;
    const int n0 = blockIdx.x * 128, m0 = blockIdx.y * 128;
    const int srow = t >> 1, shalf = (t & 1) << 4;
    const float* xsrc = X + (size_t)(m0 + srow) * KDIM + shalf;
    const int*   qsrc = Qw + (size_t)(n0 + srow) * KDIM + shalf;
    const float* scp = Sc + n0 + srow;
    const float* zpp = Zp + n0 + srow;
    _Float16* adst = As + srow * 32 + shalf;
    _Float16* bdst = Bs + srow * 32 + shalf;
    const int fr = lane & 15, fq = lane >> 4;
    const _Float16* ard = As + (wr * 64 + fr) * 32 + fq * 8;
    const _Float16* brd = Bs + (wc * 64 + fr) * 32 + fq * 8;
    f32x4 acc[4][4];
#pragma unroll
    for (int i = 0; i < 4; ++i)
#pragma unroll
        for (int j = 0; j < 4; ++j) acc[i][j] = f32x4{0.f, 0.f, 0.f, 0.f};
    for (int kt = 0; kt < KDIM / 32; ++kt) {
        const int k0 = kt * 32;
        const float4* xp = (const float4*)(xsrc + k0);
        const float4 x0 = xp[0], x1 = xp[1], x2 = xp[2], x3 = xp[3];
        const float xv[16] = {x0.x, x0.y, x0.z, x0.w, x1.x, x1.y, x1.z, x1.w,
                              x2.x, x2.y, x2.z, x2.w, x3.x, x3.y, x3.z, x3.w};
        f16x8 a0, a1;
#pragma unroll
        for (int j = 0; j < 8; ++j) { a0[j] = (_Float16)xv[j]; a1[j] = (_Float16)xv[j + 8]; }
        const int g = k0 >> 7;
        const float sf = scp[(size_t)g * NDIM];
        const float zf = zpp[(size_t)g * NDIM];
        const int4* qp = (const int4*)(qsrc + k0);
        const int4 q0 = qp[0], q1 = qp[1], q2 = qp[2], q3 = qp[3];
        const int qv[16] = {q0.x, q0.y, q0.z, q0.w, q1.x, q1.y, q1.z, q1.w,
                            q2.x, q2.y, q2.z, q2.w, q3.x, q3.y, q3.z, q3.w};
        f16x8 w0, w1;
#pragma unroll
        for (int j = 0; j < 8; ++j) {
            w0[j] = (_Float16)((float)qv[j]     * sf + zf);
            w1[j] = (_Float16)((float)qv[j + 8] * sf + zf);
        }
        *(f16x8*)adst = a0; *(f16x8*)(adst + 8) = a1;
        *(f16x8*)bdst = w0; *(f16x8*)(bdst + 8) = w1;
        __syncthreads();
        f16x8 a[4], b[4];
#pragma unroll
        for (int i = 0; i < 4; ++i) a[i] = *(const f16x8*)(ard + i * 16 * 32);
#pragma unroll
        for (int j = 0; j < 4; ++j) b[j] = *(const f16x8*)(brd + j * 16 * 32);
#pragma unroll
        for (int i = 0; i < 4; ++i)
#pragma unroll
            for (int j = 0; j < 4; ++j)
                acc[i][j] = __builtin_amdgcn_mfma_f32_16x16x32_f16(a[i], b[j], acc[i][j], 0, 0, 0);
        __syncthreads();
    }
#pragma unroll
    for (int j = 0; j < 4; ++j) {
        const int n = n0 + wc * 64 + j * 16 + fr;
        const _Float16 bv = (_Float16)Bi[n];
#pragma unroll
        for (int i = 0; i < 4; ++i) {
            const int mbase = m0 + wr * 64 + i * 16 + fq * 4;
#pragma unroll
            for (int r = 0; r < 4; ++r) {
                const _Float16 h = (_Float16)acc[i][j][r] + bv;
                Out[(size_t)(mbase + r) * NDIM + n] = (float)h;
            }
        }
    }
}

extern "C" void kernel_launch(void* const* d_in, const int* in_sizes, int n_in,
                              void* d_out, int out_size, void* d_ws, size_t ws_size,
                              hipStream_t stream) {
    const float* x  = nullptr;
    const int*   q  = nullptr;
    const float* sc = nullptr;
    const float* zp = nullptr;
    const float* bi = nullptr;
    for (int i = 0; i < n_in; ++i) {
        switch (in_sizes[i]) {
            case 33554432: x = (const float*)d_in[i]; break;
            case 45088768: q = (const int*)d_in[i]; break;
            case 352256:   if (!sc) sc = (const float*)d_in[i];
                           else     zp = (const float*)d_in[i];
                           break;
            case 11008:    bi = (const float*)d_in[i]; break;
            default: break;
        }
    }
    if (!x || !q || !sc || !zp || !bi) {
        x  = (const float*)d_in[0];
        q  = (const int*)d_in[1];
        sc = (const float*)d_in[2];
        zp = (const float*)d_in[3];
        bi = (const float*)d_in[4];
    }
    float* out = (float*)d_out;

    if (ws_size >= WS_PACKED) {
        unsigned int* pq = (unsigned int*)d_ws;
        _Float16*     xh = (_Float16*)((char*)d_ws + PQ_BYTES);
        pack_q<<<5636096 / 256, 256, 0, stream>>>(q, pq);
        cvt_x<<<33554432 / 8 / 256, 256, 0, stream>>>(x, xh);
        wq_gemm_8w<<<(TOKENS / BM) * (NDIM / BN), 512, 0, stream>>>(xh, pq, sc, zp, bi, out);
    } else {
        dim3 grid(NDIM / 128, TOKENS / 128);
        wq_gemm_direct<<<grid, dim3(256), 0, stream>>>(x, q, sc, zp, bi, out);
    }
}